// Round 12
// baseline (121.501 us; speedup 1.0000x reference)
//
#include <hip/hip_runtime.h>
#include <hip/hip_bf16.h>

#define NB 8192
#define ND 128

static constexpr float F_ALPHA  = 2.0f;
static constexpr float F_BETA   = 50.0f;
static constexpr float F_BASE   = 0.5f;
static constexpr float F_MARGIN = 0.1f;
static constexpr float LOG2E    = 1.4426950408889634f;
// exp(-A*(s-B)) = exp2(s*C1P + C0P); exp(B*(s-B)) = exp2(s*C1N + C0N)
static constexpr float C1P = -F_ALPHA * LOG2E, C0P =  F_ALPHA * F_BASE * LOG2E;
static constexpr float C1N =  F_BETA  * LOG2E, C0N = -F_BETA  * F_BASE * LOG2E;

typedef __attribute__((ext_vector_type(8))) short short8;
typedef __attribute__((ext_vector_type(4))) float f32x4;

// monotone float<->uint encoding for atomic min/max
__device__ __forceinline__ unsigned fenc(float f) {
  unsigned u = __float_as_uint(f);
  return (u & 0x80000000u) ? ~u : (u | 0x80000000u);
}
__device__ __forceinline__ float fdec(unsigned k) {
  unsigned u = (k & 0x80000000u) ? (k & 0x7FFFFFFFu) : ~k;
  return __uint_as_float(u);
}

// fp32 -> bf16 convert into MFMA-FRAGMENT-PACKED layout (proven R6/R10/R11):
// P[g][kk][lane][8 bf16], lane = q*16 + r15 holds E[g*16+r15][kk*32+q*8..+8].
// A wave's fragment load is P + ((g*4+kk)*64 + lane)*16 -> ONE coalesced
// global_load_dwordx4 with zero per-lane address math.
__global__ void k_convert(const float4* __restrict__ in, char* __restrict__ P,
                          const int* __restrict__ lab,
                          unsigned* __restrict__ pmKey, unsigned* __restrict__ nmKey,
                          float* __restrict__ pSum, float* __restrict__ nSum,
                          int* __restrict__ cnt) {
  int i = blockIdx.x * 256 + threadIdx.x;   // one float4 = 4 k-elements
  float4 v = in[i];
  __hip_bfloat16 a = __float2bfloat16(v.x), b = __float2bfloat16(v.y),
                 c = __float2bfloat16(v.z), d = __float2bfloat16(v.w);
  ushort4 o;
  o.x = *(unsigned short*)&a; o.y = *(unsigned short*)&b;
  o.z = *(unsigned short*)&c; o.w = *(unsigned short*)&d;
  const int row = i >> 5, c4 = i & 31;      // k0 = c4*4
  const int g = row >> 4, r15 = row & 15;
  const int kk = c4 >> 3, q = (c4 >> 1) & 3, j = (c4 & 1) * 4;
  *(ushort4*)(P + (((g * 4 + kk) * 64 + q * 16 + r15) * 16 + j * 2)) = o;
  if (i < NB) {
    pmKey[i] = 0xFFFFFFFFu;   // atomic-min identity
    nmKey[i] = 0u;            // atomic-max identity
    pSum[i]  = 0.f;
    nSum[i]  = 0.f;
    atomicAdd(&cnt[lab[i]], 1);
  }
}

// ZERO LDS, ZERO barriers, FULL-CHIP grid. Each wave owns 32 rows x 256
// cols, streaming 8 col-tiles of 32 from the packed buffer (every A/B load
// = ONE coalesced dwordx4; all 4 waves of a block read identical B
// addresses -> L1 hits). 2048 blocks x 4 waves = 8192 waves = exact chip
// wave capacity (VGPR ~56 <= 64 -> 8 waves/SIMD legal, LDS = 0): latency
// hidden by TLP.
// Diagonal: self counts as positive for pos_min (self-sim ~1.0 >= cross
// sims); pair existence from label histogram; pass 0 stores the MFMA-exact
// self-sim; k_final subtracts self's conditional hard-pos term.
template<int PASS>
__global__ __launch_bounds__(256, 2)
void k_simpass(const char* __restrict__ P,
               const int* __restrict__ lab,
               unsigned* __restrict__ pmKey,
               unsigned* __restrict__ nmKey,
               float* __restrict__ pSum,
               float* __restrict__ nSum,
               float* __restrict__ selfSim)
{
  const int t    = threadIdx.x;
  const int lane = t & 63, wid = t >> 6;
  const int q    = lane >> 4, r15 = lane & 15;
  const int rBase = blockIdx.y * 128 + wid * 32;   // wave-exclusive 32 rows
  const int cBase = blockIdx.x * 256;

  // A fragments: 2 row-groups x 4 kk -> 8 coalesced dwordx4 (32 VGPR)
  short8 afr[4][2];
#pragma unroll
  for (int mi = 0; mi < 2; ++mi) {
    const char* pa = P + (size_t)(((rBase >> 4) + mi) * 4) * 1024 + lane * 16;
#pragma unroll
    for (int kk = 0; kk < 4; ++kk)
      afr[kk][mi] = *(const short8*)(pa + kk * 1024);
  }

  // per-lane row data (C-rows: mi*16 + q*4 + rg); margins pre-folded
  int lrr[8]; float pmr[8], nmr[8];
#pragma unroll
  for (int mi = 0; mi < 2; ++mi)
#pragma unroll
    for (int rg = 0; rg < 4; ++rg) {
      int r = rBase + mi * 16 + q * 4 + rg;
      lrr[mi * 4 + rg] = lab[r];
      if (PASS == 1) {
        pmr[mi * 4 + rg] = fdec(pmKey[r]) - F_MARGIN;  // hn: s > pm - M
        nmr[mi * 4 + rg] = fdec(nmKey[r]) + F_MARGIN;  // hp: s < nm + M
      }
    }

  float st1[8], st2[8];
#pragma unroll
  for (int i = 0; i < 8; ++i) {
    st1[i] = (PASS == 0) ?  __builtin_inff() : 0.f;
    st2[i] = (PASS == 0) ? -__builtin_inff() : 0.f;
  }

#pragma unroll 1   // flat live set; TLP hides per-tile latency
  for (int ct = 0; ct < 8; ++ct) {
    const int cTile = cBase + ct * 32;
    const char* pb = P + (size_t)((cTile >> 4) * 4) * 1024 + lane * 16;

    int cl[2];
    cl[0] = lab[cTile + r15];
    cl[1] = lab[cTile + 16 + r15];

    f32x4 acc[2][2];
#pragma unroll
    for (int mi = 0; mi < 2; ++mi) {
      acc[mi][0] = (f32x4){0.f, 0.f, 0.f, 0.f};
      acc[mi][1] = (f32x4){0.f, 0.f, 0.f, 0.f};
    }

#pragma unroll
    for (int kk = 0; kk < 4; ++kk) {
      short8 b0 = *(const short8*)(pb + kk * 1024);           // col group 0
      short8 b1 = *(const short8*)(pb + 4096 + kk * 1024);    // col group 1
#pragma unroll
      for (int mi = 0; mi < 2; ++mi) {
        acc[mi][0] = __builtin_amdgcn_mfma_f32_16x16x32_bf16(afr[kk][mi], b0, acc[mi][0], 0, 0, 0);
        acc[mi][1] = __builtin_amdgcn_mfma_f32_16x16x32_bf16(afr[kk][mi], b1, acc[mi][1], 0, 0, 0);
      }
    }

    // branchless fold (self acts as a positive; no diagonal compare)
#pragma unroll
    for (int mi = 0; mi < 2; ++mi)
#pragma unroll
      for (int rg = 0; rg < 4; ++rg) {
        const int idx = mi * 4 + rg;
        const int lr  = lrr[idx];
#pragma unroll
        for (int ni = 0; ni < 2; ++ni) {
          float s = acc[mi][ni][rg];
          bool same = (lr == cl[ni]);
          if (PASS == 0) {
            st1[idx] = fminf(st1[idx], same ? s :  __builtin_inff());
            st2[idx] = fmaxf(st2[idx], same ? -__builtin_inff() : s);
          } else {
            bool hp = same  && (s < nmr[idx]);
            bool hn = !same && (s > pmr[idx]);
            float e = __builtin_amdgcn_exp2f(
                fmaf(s, same ? C1P : C1N, same ? C0P : C0N));
            st1[idx] += hp ? e : 0.f;
            st2[idx] += hn ? e : 0.f;
          }
        }
      }

    // capture MFMA-exact diagonal (wave-uniform branch; rBase and cTile
    // both 32-aligned so the diagonal tile is exactly cTile==rBase)
    if (PASS == 0 && cTile == rBase) {
#pragma unroll
      for (int mi = 0; mi < 2; ++mi)
#pragma unroll
        for (int rg = 0; rg < 4; ++rg)
          if (r15 == q * 4 + rg)
            selfSim[rBase + mi * 16 + q * 4 + rg] = acc[mi][mi][rg];
    }
  }

  // epilogue: rows wave-exclusive -> 16-lane shuffle reduce + one atomic/row
#pragma unroll
  for (int mi = 0; mi < 2; ++mi)
#pragma unroll
    for (int rg = 0; rg < 4; ++rg) {
      const int idx = mi * 4 + rg;
      const int r   = rBase + mi * 16 + q * 4 + rg;
      float v1 = st1[idx], v2 = st2[idx];
      if (PASS == 0) {
#pragma unroll
        for (int d = 1; d < 16; d <<= 1) {
          v1 = fminf(v1, __shfl_xor(v1, d));
          v2 = fmaxf(v2, __shfl_xor(v2, d));
        }
        if (r15 == 0) {
          atomicMin(&pmKey[r], fenc(v1));
          atomicMax(&nmKey[r], fenc(v2));
        }
      } else {
#pragma unroll
        for (int d = 1; d < 16; d <<= 1) {
          v1 += __shfl_xor(v1, d);
          v2 += __shfl_xor(v2, d);
        }
        if (r15 == 0) {
          if (v1 != 0.f) atomicAdd(&pSum[r], v1);
          if (v2 != 0.f) atomicAdd(&nSum[r], v2);
        }
      }
    }
}

__global__ void k_final(const unsigned* __restrict__ pmKey,
                        const unsigned* __restrict__ nmKey,
                        const float* __restrict__ pSum,
                        const float* __restrict__ nSum,
                        const float* __restrict__ selfSim,
                        const int* __restrict__ lab,
                        const int* __restrict__ cnt,
                        float* __restrict__ out)
{
  const int t = threadIdx.x;
  float ls = 0.f, nv = 0.f;
  for (int r = t; r < NB; r += 1024) {
    int c = cnt[lab[r]];
    unsigned nk = nmKey[r];
    bool pe = (c > 1);                 // a true positive pair exists
    bool ne = (c < NB) && (nk > 0x007FFFFFu);
    if (pe && ne) {
      float pm = fdec(pmKey[r]), nm = fdec(nk);
      if (pm - F_MARGIN < nm) {        // hard_pos.any <=> hard_neg.any
        float ss = selfSim[r];
        float psub = (ss - F_MARGIN < nm)
                       ? __builtin_amdgcn_exp2f(fmaf(ss, C1P, C0P)) : 0.f;
        float ps = fmaxf(pSum[r] - psub, 0.f);
        ls += log1pf(ps) * (1.0f / F_ALPHA) + log1pf(nSum[r]) * (1.0f / F_BETA);
        nv += 1.f;
      }
    }
  }
#pragma unroll
  for (int d = 1; d < 64; d <<= 1) {
    ls += __shfl_xor(ls, d);
    nv += __shfl_xor(nv, d);
  }
  __shared__ float sL[16], sC[16];
  if ((t & 63) == 0) { sL[t >> 6] = ls; sC[t >> 6] = nv; }
  __syncthreads();
  if (t == 0) {
    float a = 0.f, c = 0.f;
#pragma unroll
    for (int w = 0; w < 16; ++w) { a += sL[w]; c += sC[w]; }
    out[0] = a / fmaxf(c, 1.f);
  }
}

extern "C" void kernel_launch(void* const* d_in, const int* in_sizes, int n_in,
                              void* d_out, int out_size, void* d_ws, size_t ws_size,
                              hipStream_t stream)
{
  const float* emb = (const float*)d_in[0];
  const int*   lab = (const int*)d_in[1];
  float* out = (float*)d_out;

  char* ws = (char*)d_ws;
  char*     P       = ws;                                       // 2 MB packed
  unsigned* pmKey   = (unsigned*)(ws + 2097152);                // 32 KB
  unsigned* nmKey   = (unsigned*)(ws + 2097152 + 32768);        // 32 KB
  float*    pSum    = (float*)(ws + 2097152 + 65536);           // 32 KB
  float*    nSum    = (float*)(ws + 2097152 + 98304);           // 32 KB
  float*    selfSim = (float*)(ws + 2097152 + 131072);          // 32 KB
  int*      cnt     = (int*)(ws + 2097152 + 163840);            // 2 KB

  hipMemsetAsync(cnt, 0, 512 * sizeof(int), stream);
  k_convert<<<NB * ND / (256 * 4), 256, 0, stream>>>(
      (const float4*)emb, P, lab, pmKey, nmKey, pSum, nSum, cnt);

  dim3 grid(32, 64);   // 2048 blocks x 4 waves = 8192 waves = chip capacity
  k_simpass<0><<<grid, 256, 0, stream>>>(P, lab, pmKey, nmKey, pSum, nSum, selfSim);
  k_simpass<1><<<grid, 256, 0, stream>>>(P, lab, pmKey, nmKey, pSum, nSum, selfSim);
  k_final<<<1, 1024, 0, stream>>>(pmKey, nmKey, pSum, nSum, selfSim, lab, cnt, out);
}

// Round 14
// 94.740 us; speedup vs baseline: 1.2825x; 1.2825x over previous
//
#include <hip/hip_runtime.h>
#include <hip/hip_bf16.h>

#define NB 8192
#define ND 128

static constexpr float F_ALPHA  = 2.0f;
static constexpr float F_BETA   = 50.0f;
static constexpr float F_BASE   = 0.5f;
static constexpr float F_MARGIN = 0.1f;
static constexpr float LOG2E    = 1.4426950408889634f;
// exp(-A*(s-B)) = exp2(s*C1P + C0P); exp(B*(s-B)) = exp2(s*C1N + C0N)
static constexpr float C1P = -F_ALPHA * LOG2E, C0P =  F_ALPHA * F_BASE * LOG2E;
static constexpr float C1N =  F_BETA  * LOG2E, C0N = -F_BETA  * F_BASE * LOG2E;

typedef __attribute__((ext_vector_type(8))) short short8;
typedef __attribute__((ext_vector_type(4))) float f32x4;

// monotone float<->uint encoding for atomic min/max
__device__ __forceinline__ unsigned fenc(float f) {
  unsigned u = __float_as_uint(f);
  return (u & 0x80000000u) ? ~u : (u | 0x80000000u);
}
__device__ __forceinline__ float fdec(unsigned k) {
  unsigned u = (k & 0x80000000u) ? (k & 0x7FFFFFFFu) : ~k;
  return __uint_as_float(u);
}

// fp32 -> bf16 convert into MFMA-FRAGMENT-PACKED layout (proven R6/R10/R11):
// P[g][kk][lane][8 bf16], lane = q*16 + r15 holds E[g*16+r15][kk*32+q*8..+8].
// A wave's fragment load is P + ((g*4+kk)*64 + lane)*16 -> ONE coalesced
// global_load_dwordx4 with zero per-lane address math.
__global__ void k_convert(const float4* __restrict__ in, char* __restrict__ P,
                          const int* __restrict__ lab,
                          unsigned* __restrict__ pmKey, unsigned* __restrict__ nmKey,
                          float* __restrict__ pSum, float* __restrict__ nSum,
                          int* __restrict__ cnt) {
  int i = blockIdx.x * 256 + threadIdx.x;   // one float4 = 4 k-elements
  float4 v = in[i];
  __hip_bfloat16 a = __float2bfloat16(v.x), b = __float2bfloat16(v.y),
                 c = __float2bfloat16(v.z), d = __float2bfloat16(v.w);
  ushort4 o;
  o.x = *(unsigned short*)&a; o.y = *(unsigned short*)&b;
  o.z = *(unsigned short*)&c; o.w = *(unsigned short*)&d;
  const int row = i >> 5, c4 = i & 31;      // k0 = c4*4
  const int g = row >> 4, r15 = row & 15;
  const int kk = c4 >> 3, q = (c4 >> 1) & 3, j = (c4 & 1) * 4;
  *(ushort4*)(P + (((g * 4 + kk) * 64 + q * 16 + r15) * 16 + j * 2)) = o;
  if (i < NB) {
    pmKey[i] = 0xFFFFFFFFu;   // atomic-min identity
    nmKey[i] = 0u;            // atomic-max identity
    pSum[i]  = 0.f;
    nSum[i]  = 0.f;
    atomicAdd(&cnt[lab[i]], 1);
  }
}

// ZERO LDS, ZERO barriers + software pipeline, R11 geometry (wave = 32 rows
// x 512 cols, 16 tiles of 32). Per tile: {MFMA on already-loaded b -> issue
// NEXT tile's b+label loads -> fold}, so each tile's loads get the whole
// fold (~200+ cyc) as lead time. acc init through the kk=0 MFMA with a
// loop-invariant zero C (no per-tile movs). Every A/B load = ONE coalesced
// dwordx4 from the packed buffer.
// Diagonal: self counts as positive for pos_min (self-sim ~1.0 >= cross
// sims); pair existence from label histogram; pass 0 stores the MFMA-exact
// self-sim; k_final subtracts self's conditional hard-pos term.
template<int PASS>
__global__ __launch_bounds__(256, 2)
void k_simpass(const char* __restrict__ P,
               const int* __restrict__ lab,
               unsigned* __restrict__ pmKey,
               unsigned* __restrict__ nmKey,
               float* __restrict__ pSum,
               float* __restrict__ nSum,
               float* __restrict__ selfSim)
{
  const int t    = threadIdx.x;
  const int lane = t & 63, wid = t >> 6;
  const int q    = lane >> 4, r15 = lane & 15;
  const int rBase = blockIdx.y * 128 + wid * 32;   // wave-exclusive 32 rows
  const int cBase = blockIdx.x * 512;              // 512 cols per wave

  // A fragments: 2 row-groups x 4 kk -> 8 coalesced dwordx4 (32 VGPR)
  short8 afr[4][2];
#pragma unroll
  for (int mi = 0; mi < 2; ++mi) {
    const char* pa = P + (size_t)(((rBase >> 4) + mi) * 4) * 1024 + lane * 16;
#pragma unroll
    for (int kk = 0; kk < 4; ++kk)
      afr[kk][mi] = *(const short8*)(pa + kk * 1024);
  }

  // per-lane row data (C-rows: mi*16 + q*4 + rg); margins pre-folded
  int lrr[8]; float pmr[8], nmr[8];
#pragma unroll
  for (int mi = 0; mi < 2; ++mi)
#pragma unroll
    for (int rg = 0; rg < 4; ++rg) {
      int r = rBase + mi * 16 + q * 4 + rg;
      lrr[mi * 4 + rg] = lab[r];
      if (PASS == 1) {
        pmr[mi * 4 + rg] = fdec(pmKey[r]) - F_MARGIN;  // hn: s > pm - M
        nmr[mi * 4 + rg] = fdec(nmKey[r]) + F_MARGIN;  // hp: s < nm + M
      }
    }

  float st1[8], st2[8];
#pragma unroll
  for (int i = 0; i < 8; ++i) {
    st1[i] = (PASS == 0) ?  __builtin_inff() : 0.f;
    st2[i] = (PASS == 0) ? -__builtin_inff() : 0.f;
  }

  const char* pbase = P + (size_t)cBase * 256 + lane * 16;

  // ---- pipeline prologue: loads for tile 0 ----
  short8 b[8];            // [ni*4+kk], single buffer (consumed by MFMA)
#pragma unroll
  for (int u = 0; u < 4; ++u) {
    b[u]     = *(const short8*)(pbase + u * 1024);
    b[4 + u] = *(const short8*)(pbase + 4096 + u * 1024);
  }
  int clN0 = lab[cBase + r15];
  int clN1 = lab[cBase + 16 + r15];

  const f32x4 Z4 = (f32x4){0.f, 0.f, 0.f, 0.f};   // loop-invariant zero C

#pragma unroll 1   // flat live set; pipeline + TLP hide latency
  for (int ct = 0; ct < 16; ++ct) {
    const int cTile = cBase + ct * 32;

    // MFMA on the already-loaded b; kk=0 initializes acc through Z4
    f32x4 acc[2][2];
#pragma unroll
    for (int mi = 0; mi < 2; ++mi) {
      acc[mi][0] = __builtin_amdgcn_mfma_f32_16x16x32_bf16(afr[0][mi], b[0], Z4, 0, 0, 0);
      acc[mi][1] = __builtin_amdgcn_mfma_f32_16x16x32_bf16(afr[0][mi], b[4], Z4, 0, 0, 0);
    }
#pragma unroll
    for (int kk = 1; kk < 4; ++kk)
#pragma unroll
      for (int mi = 0; mi < 2; ++mi) {
        acc[mi][0] = __builtin_amdgcn_mfma_f32_16x16x32_bf16(afr[kk][mi], b[kk],     acc[mi][0], 0, 0, 0);
        acc[mi][1] = __builtin_amdgcn_mfma_f32_16x16x32_bf16(afr[kk][mi], b[4 + kk], acc[mi][1], 0, 0, 0);
      }

    const int cl0 = clN0, cl1 = clN1;   // labels for THIS tile

    // issue NEXT tile's loads now — they complete under the fold below
    if (ct < 15) {
      const char* pn = pbase + (size_t)(ct + 1) * 8192;
#pragma unroll
      for (int u = 0; u < 4; ++u) {
        b[u]     = *(const short8*)(pn + u * 1024);
        b[4 + u] = *(const short8*)(pn + 4096 + u * 1024);
      }
      clN0 = lab[cTile + 32 + r15];
      clN1 = lab[cTile + 48 + r15];
    }

    // branchless fold (self acts as a positive; no diagonal compare)
#pragma unroll
    for (int mi = 0; mi < 2; ++mi)
#pragma unroll
      for (int rg = 0; rg < 4; ++rg) {
        const int idx = mi * 4 + rg;
        const int lr  = lrr[idx];
        const float s0 = acc[mi][0][rg], s1 = acc[mi][1][rg];
        const bool same0 = (lr == cl0), same1 = (lr == cl1);
        if (PASS == 0) {
          // nested min/max -> v_min3/v_max3 fusion
          float x0 = same0 ? s0 :  __builtin_inff();
          float x1 = same1 ? s1 :  __builtin_inff();
          st1[idx] = fminf(fminf(st1[idx], x0), x1);
          float y0 = same0 ? -__builtin_inff() : s0;
          float y1 = same1 ? -__builtin_inff() : s1;
          st2[idx] = fmaxf(fmaxf(st2[idx], y0), y1);
        } else {
          float e0 = __builtin_amdgcn_exp2f(
              fmaf(s0, same0 ? C1P : C1N, same0 ? C0P : C0N));
          float e1 = __builtin_amdgcn_exp2f(
              fmaf(s1, same1 ? C1P : C1N, same1 ? C0P : C0N));
          bool hp0 = same0 && (s0 < nmr[idx]), hn0 = !same0 && (s0 > pmr[idx]);
          bool hp1 = same1 && (s1 < nmr[idx]), hn1 = !same1 && (s1 > pmr[idx]);
          st1[idx] += (hp0 ? e0 : 0.f) + (hp1 ? e1 : 0.f);
          st2[idx] += (hn0 ? e0 : 0.f) + (hn1 ? e1 : 0.f);
        }
      }

    // capture MFMA-exact diagonal (wave-uniform branch; both 32-aligned)
    if (PASS == 0 && cTile == rBase) {
#pragma unroll
      for (int mi = 0; mi < 2; ++mi)
#pragma unroll
        for (int rg = 0; rg < 4; ++rg)
          if (r15 == q * 4 + rg)
            selfSim[rBase + mi * 16 + q * 4 + rg] = acc[mi][mi][rg];
    }
  }

  // epilogue: rows wave-exclusive -> 16-lane shuffle reduce + one atomic/row
#pragma unroll
  for (int mi = 0; mi < 2; ++mi)
#pragma unroll
    for (int rg = 0; rg < 4; ++rg) {
      const int idx = mi * 4 + rg;
      const int r   = rBase + mi * 16 + q * 4 + rg;
      float v1 = st1[idx], v2 = st2[idx];
      if (PASS == 0) {
#pragma unroll
        for (int d = 1; d < 16; d <<= 1) {
          v1 = fminf(v1, __shfl_xor(v1, d));
          v2 = fmaxf(v2, __shfl_xor(v2, d));
        }
        if (r15 == 0) {
          atomicMin(&pmKey[r], fenc(v1));
          atomicMax(&nmKey[r], fenc(v2));
        }
      } else {
#pragma unroll
        for (int d = 1; d < 16; d <<= 1) {
          v1 += __shfl_xor(v1, d);
          v2 += __shfl_xor(v2, d);
        }
        if (r15 == 0) {
          if (v1 != 0.f) atomicAdd(&pSum[r], v1);
          if (v2 != 0.f) atomicAdd(&nSum[r], v2);
        }
      }
    }
}

__global__ void k_final(const unsigned* __restrict__ pmKey,
                        const unsigned* __restrict__ nmKey,
                        const float* __restrict__ pSum,
                        const float* __restrict__ nSum,
                        const float* __restrict__ selfSim,
                        const int* __restrict__ lab,
                        const int* __restrict__ cnt,
                        float* __restrict__ out)
{
  const int t = threadIdx.x;
  float ls = 0.f, nv = 0.f;
  for (int r = t; r < NB; r += 1024) {
    int c = cnt[lab[r]];
    unsigned nk = nmKey[r];
    bool pe = (c > 1);                 // a true positive pair exists
    bool ne = (c < NB) && (nk > 0x007FFFFFu);
    if (pe && ne) {
      float pm = fdec(pmKey[r]), nm = fdec(nk);
      if (pm - F_MARGIN < nm) {        // hard_pos.any <=> hard_neg.any
        float ss = selfSim[r];
        float psub = (ss - F_MARGIN < nm)
                       ? __builtin_amdgcn_exp2f(fmaf(ss, C1P, C0P)) : 0.f;
        float ps = fmaxf(pSum[r] - psub, 0.f);
        ls += log1pf(ps) * (1.0f / F_ALPHA) + log1pf(nSum[r]) * (1.0f / F_BETA);
        nv += 1.f;
      }
    }
  }
#pragma unroll
  for (int d = 1; d < 64; d <<= 1) {
    ls += __shfl_xor(ls, d);
    nv += __shfl_xor(nv, d);
  }
  __shared__ float sL[16], sC[16];
  if ((t & 63) == 0) { sL[t >> 6] = ls; sC[t >> 6] = nv; }
  __syncthreads();
  if (t == 0) {
    float a = 0.f, c = 0.f;
#pragma unroll
    for (int w = 0; w < 16; ++w) { a += sL[w]; c += sC[w]; }
    out[0] = a / fmaxf(c, 1.f);
  }
}

extern "C" void kernel_launch(void* const* d_in, const int* in_sizes, int n_in,
                              void* d_out, int out_size, void* d_ws, size_t ws_size,
                              hipStream_t stream)
{
  const float* emb = (const float*)d_in[0];
  const int*   lab = (const int*)d_in[1];
  float* out = (float*)d_out;

  char* ws = (char*)d_ws;
  char*     P       = ws;                                       // 2 MB packed
  unsigned* pmKey   = (unsigned*)(ws + 2097152);                // 32 KB
  unsigned* nmKey   = (unsigned*)(ws + 2097152 + 32768);        // 32 KB
  float*    pSum    = (float*)(ws + 2097152 + 65536);           // 32 KB
  float*    nSum    = (float*)(ws + 2097152 + 98304);           // 32 KB
  float*    selfSim = (float*)(ws + 2097152 + 131072);          // 32 KB
  int*      cnt     = (int*)(ws + 2097152 + 163840);            // 2 KB

  hipMemsetAsync(cnt, 0, 512 * sizeof(int), stream);
  k_convert<<<NB * ND / (256 * 4), 256, 0, stream>>>(
      (const float4*)emb, P, lab, pmKey, nmKey, pSum, nSum, cnt);

  dim3 grid(16, 64);   // 16 col-chunks(512 cols) x 64 row-blocks = R11 geometry
  k_simpass<0><<<grid, 256, 0, stream>>>(P, lab, pmKey, nmKey, pSum, nSum, selfSim);
  k_simpass<1><<<grid, 256, 0, stream>>>(P, lab, pmKey, nmKey, pSum, nSum, selfSim);
  k_final<<<1, 1024, 0, stream>>>(pmKey, nmKey, pSum, nSum, selfSim, lab, cnt, out);
}

// Round 15
// 93.049 us; speedup vs baseline: 1.3058x; 1.0182x over previous
//
#include <hip/hip_runtime.h>
#include <hip/hip_bf16.h>

#define NB 8192
#define ND 128

static constexpr float F_ALPHA  = 2.0f;
static constexpr float F_BETA   = 50.0f;
static constexpr float F_BASE   = 0.5f;
static constexpr float F_MARGIN = 0.1f;
static constexpr float LOG2E    = 1.4426950408889634f;
// exp(-A*(s-B)) = exp2(s*C1P + C0P); exp(B*(s-B)) = exp2(s*C1N + C0N)
static constexpr float C1P = -F_ALPHA * LOG2E, C0P =  F_ALPHA * F_BASE * LOG2E;
static constexpr float C1N =  F_BETA  * LOG2E, C0N = -F_BETA  * F_BASE * LOG2E;

typedef __attribute__((ext_vector_type(8))) short short8;
typedef __attribute__((ext_vector_type(4))) float f32x4;

// monotone float<->uint encoding for atomic min/max
__device__ __forceinline__ unsigned fenc(float f) {
  unsigned u = __float_as_uint(f);
  return (u & 0x80000000u) ? ~u : (u | 0x80000000u);
}
__device__ __forceinline__ float fdec(unsigned k) {
  unsigned u = (k & 0x80000000u) ? (k & 0x7FFFFFFFu) : ~k;
  return __uint_as_float(u);
}

__device__ __forceinline__ void async16(const void* g, void* l) {
  __builtin_amdgcn_global_load_lds(
      (const __attribute__((address_space(1))) void*)g,
      (__attribute__((address_space(3))) void*)l, 16, 0, 0);
}

// fp32 -> bf16 convert into MFMA-FRAGMENT-PACKED layout (proven R6/R10-R14):
// P[g][kk][lane][8 bf16], lane = q*16 + r15 holds E[g*16+r15][kk*32+q*8..+8].
// A 32-col x 128-K tile = 8 KB CONTIGUOUS in P.
__global__ void k_convert(const float4* __restrict__ in, char* __restrict__ P,
                          const int* __restrict__ lab,
                          unsigned* __restrict__ pmKey, unsigned* __restrict__ nmKey,
                          float* __restrict__ pSum, float* __restrict__ nSum,
                          int* __restrict__ cnt) {
  int i = blockIdx.x * 256 + threadIdx.x;   // one float4 = 4 k-elements
  float4 v = in[i];
  __hip_bfloat16 a = __float2bfloat16(v.x), b = __float2bfloat16(v.y),
                 c = __float2bfloat16(v.z), d = __float2bfloat16(v.w);
  ushort4 o;
  o.x = *(unsigned short*)&a; o.y = *(unsigned short*)&b;
  o.z = *(unsigned short*)&c; o.w = *(unsigned short*)&d;
  const int row = i >> 5, c4 = i & 31;      // k0 = c4*4
  const int g = row >> 4, r15 = row & 15;
  const int kk = c4 >> 3, q = (c4 >> 1) & 3, j = (c4 & 1) * 4;
  *(ushort4*)(P + (((g * 4 + kk) * 64 + q * 16 + r15) * 16 + j * 2)) = o;
  if (i < NB) {
    pmKey[i] = 0xFFFFFFFFu;   // atomic-min identity
    nmKey[i] = 0u;            // atomic-max identity
    pSum[i]  = 0.f;
    nSum[i]  = 0.f;
    atomicAdd(&cnt[lab[i]], 1);
  }
}

// LDS-shared B stream + software pipeline. Block = 4 waves x 32 rows =
// 128 rows, 512 cols as 16 tiles of 32. Each 8 KB B-tile is staged ONCE
// into LDS (2 async16/thread, contiguous source, zero address math) and
// consumed by all 4 waves -> L2 B-traffic drops 4x vs R14. Double buffer,
// one barrier per tile; next tile's stage issued BEFORE consuming current,
// so the barrier's vmcnt drain is covered by ds_read+MFMA+fold. ds_read is
// lane*16 + imm (conflict-free m134 pattern).
// Diagonal: self counts as positive for pos_min (self-sim ~1.0 >= cross
// sims); pair existence from label histogram; pass 0 stores the MFMA-exact
// self-sim; k_final subtracts self's conditional hard-pos term.
template<int PASS>
__global__ __launch_bounds__(256, 2)
void k_simpass(const char* __restrict__ P,
               const int* __restrict__ lab,
               unsigned* __restrict__ pmKey,
               unsigned* __restrict__ nmKey,
               float* __restrict__ pSum,
               float* __restrict__ nSum,
               float* __restrict__ selfSim)
{
  __shared__ __align__(16) char sB[2][8192];   // 2 x (32 cols x 128 K packed)

  const int t    = threadIdx.x;
  const int lane = t & 63, wid = t >> 6;
  const int q    = lane >> 4, r15 = lane & 15;
  const int rBase = blockIdx.y * 128 + wid * 32;   // wave-exclusive 32 rows
  const int cBase = blockIdx.x * 512;

  const char* gB = P + (size_t)cBase * 256;   // block's 128 KB B-panel

  // ---- prologue: stage tile 0 (linear copy, wave-uniform LDS dest) ----
  async16(gB + wid * 1024 + lane * 16,        &sB[0][0] + wid * 1024);
  async16(gB + 4096 + wid * 1024 + lane * 16, &sB[0][0] + 4096 + wid * 1024);

  // A fragments: 2 row-groups x 4 kk -> 8 coalesced dwordx4 (32 VGPR)
  short8 afr[4][2];
#pragma unroll
  for (int mi = 0; mi < 2; ++mi) {
    const char* pa = P + (size_t)(((rBase >> 4) + mi) * 4) * 1024 + lane * 16;
#pragma unroll
    for (int kk = 0; kk < 4; ++kk)
      afr[kk][mi] = *(const short8*)(pa + kk * 1024);
  }

  // per-lane row data (C-rows: mi*16 + q*4 + rg); margins pre-folded
  int lrr[8]; float pmr[8], nmr[8];
#pragma unroll
  for (int mi = 0; mi < 2; ++mi)
#pragma unroll
    for (int rg = 0; rg < 4; ++rg) {
      int r = rBase + mi * 16 + q * 4 + rg;
      lrr[mi * 4 + rg] = lab[r];
      if (PASS == 1) {
        pmr[mi * 4 + rg] = fdec(pmKey[r]) - F_MARGIN;  // hn: s > pm - M
        nmr[mi * 4 + rg] = fdec(nmKey[r]) + F_MARGIN;  // hp: s < nm + M
      }
    }

  float st1[8], st2[8];
#pragma unroll
  for (int i = 0; i < 8; ++i) {
    st1[i] = (PASS == 0) ?  __builtin_inff() : 0.f;
    st2[i] = (PASS == 0) ? -__builtin_inff() : 0.f;
  }

  int clN0 = lab[cBase + r15];
  int clN1 = lab[cBase + 16 + r15];

  const f32x4 Z4 = (f32x4){0.f, 0.f, 0.f, 0.f};   // loop-invariant zero C

  __syncthreads();   // tile 0 staged (vmcnt drained by syncthreads)

#pragma unroll 1
  for (int ct = 0; ct < 16; ++ct) {
    const int buf = ct & 1;
    const int cTile = cBase + ct * 32;

    // issue NEXT tile's stage FIRST — completes under ds_read+MFMA+fold
    if (ct < 15) {
      const char* gn = gB + (size_t)(ct + 1) * 8192;
      async16(gn + wid * 1024 + lane * 16,        &sB[buf ^ 1][0] + wid * 1024);
      async16(gn + 4096 + wid * 1024 + lane * 16, &sB[buf ^ 1][0] + 4096 + wid * 1024);
    }

    // B fragments from LDS: lane*16 + compile-time offsets, conflict-free
    const char* sb = &sB[buf][0] + lane * 16;
    short8 b[8];
#pragma unroll
    for (int kk = 0; kk < 4; ++kk) {
      b[kk]     = *(const short8*)(sb + kk * 1024);
      b[4 + kk] = *(const short8*)(sb + 4096 + kk * 1024);
    }

    // MFMA; kk=0 initializes acc through Z4 (no per-tile movs)
    f32x4 acc[2][2];
#pragma unroll
    for (int mi = 0; mi < 2; ++mi) {
      acc[mi][0] = __builtin_amdgcn_mfma_f32_16x16x32_bf16(afr[0][mi], b[0], Z4, 0, 0, 0);
      acc[mi][1] = __builtin_amdgcn_mfma_f32_16x16x32_bf16(afr[0][mi], b[4], Z4, 0, 0, 0);
    }
#pragma unroll
    for (int kk = 1; kk < 4; ++kk)
#pragma unroll
      for (int mi = 0; mi < 2; ++mi) {
        acc[mi][0] = __builtin_amdgcn_mfma_f32_16x16x32_bf16(afr[kk][mi], b[kk],     acc[mi][0], 0, 0, 0);
        acc[mi][1] = __builtin_amdgcn_mfma_f32_16x16x32_bf16(afr[kk][mi], b[4 + kk], acc[mi][1], 0, 0, 0);
      }

    const int cl0 = clN0, cl1 = clN1;   // labels for THIS tile
    if (ct < 15) {                       // pipeline next labels
      clN0 = lab[cTile + 32 + r15];
      clN1 = lab[cTile + 48 + r15];
    }

    // branchless fold (self acts as a positive; no diagonal compare)
#pragma unroll
    for (int mi = 0; mi < 2; ++mi)
#pragma unroll
      for (int rg = 0; rg < 4; ++rg) {
        const int idx = mi * 4 + rg;
        const int lr  = lrr[idx];
        const float s0 = acc[mi][0][rg], s1 = acc[mi][1][rg];
        const bool same0 = (lr == cl0), same1 = (lr == cl1);
        if (PASS == 0) {
          float x0 = same0 ? s0 :  __builtin_inff();
          float x1 = same1 ? s1 :  __builtin_inff();
          st1[idx] = fminf(fminf(st1[idx], x0), x1);
          float y0 = same0 ? -__builtin_inff() : s0;
          float y1 = same1 ? -__builtin_inff() : s1;
          st2[idx] = fmaxf(fmaxf(st2[idx], y0), y1);
        } else {
          float e0 = __builtin_amdgcn_exp2f(
              fmaf(s0, same0 ? C1P : C1N, same0 ? C0P : C0N));
          float e1 = __builtin_amdgcn_exp2f(
              fmaf(s1, same1 ? C1P : C1N, same1 ? C0P : C0N));
          bool hp0 = same0 && (s0 < nmr[idx]), hn0 = !same0 && (s0 > pmr[idx]);
          bool hp1 = same1 && (s1 < nmr[idx]), hn1 = !same1 && (s1 > pmr[idx]);
          st1[idx] += (hp0 ? e0 : 0.f) + (hp1 ? e1 : 0.f);
          st2[idx] += (hn0 ? e0 : 0.f) + (hn1 ? e1 : 0.f);
        }
      }

    // capture MFMA-exact diagonal (wave-uniform branch; both 32-aligned)
    if (PASS == 0 && cTile == rBase) {
#pragma unroll
      for (int mi = 0; mi < 2; ++mi)
#pragma unroll
        for (int rg = 0; rg < 4; ++rg)
          if (r15 == q * 4 + rg)
            selfSim[rBase + mi * 16 + q * 4 + rg] = acc[mi][mi][rg];
    }

    __syncthreads();   // next buffer staged; all reads of current done
  }

  // epilogue: rows wave-exclusive -> 16-lane shuffle reduce + one atomic/row
#pragma unroll
  for (int mi = 0; mi < 2; ++mi)
#pragma unroll
    for (int rg = 0; rg < 4; ++rg) {
      const int idx = mi * 4 + rg;
      const int r   = rBase + mi * 16 + q * 4 + rg;
      float v1 = st1[idx], v2 = st2[idx];
      if (PASS == 0) {
#pragma unroll
        for (int d = 1; d < 16; d <<= 1) {
          v1 = fminf(v1, __shfl_xor(v1, d));
          v2 = fmaxf(v2, __shfl_xor(v2, d));
        }
        if (r15 == 0) {
          atomicMin(&pmKey[r], fenc(v1));
          atomicMax(&nmKey[r], fenc(v2));
        }
      } else {
#pragma unroll
        for (int d = 1; d < 16; d <<= 1) {
          v1 += __shfl_xor(v1, d);
          v2 += __shfl_xor(v2, d);
        }
        if (r15 == 0) {
          if (v1 != 0.f) atomicAdd(&pSum[r], v1);
          if (v2 != 0.f) atomicAdd(&nSum[r], v2);
        }
      }
    }
}

__global__ void k_final(const unsigned* __restrict__ pmKey,
                        const unsigned* __restrict__ nmKey,
                        const float* __restrict__ pSum,
                        const float* __restrict__ nSum,
                        const float* __restrict__ selfSim,
                        const int* __restrict__ lab,
                        const int* __restrict__ cnt,
                        float* __restrict__ out)
{
  const int t = threadIdx.x;
  float ls = 0.f, nv = 0.f;
  for (int r = t; r < NB; r += 1024) {
    int c = cnt[lab[r]];
    unsigned nk = nmKey[r];
    bool pe = (c > 1);                 // a true positive pair exists
    bool ne = (c < NB) && (nk > 0x007FFFFFu);
    if (pe && ne) {
      float pm = fdec(pmKey[r]), nm = fdec(nk);
      if (pm - F_MARGIN < nm) {        // hard_pos.any <=> hard_neg.any
        float ss = selfSim[r];
        float psub = (ss - F_MARGIN < nm)
                       ? __builtin_amdgcn_exp2f(fmaf(ss, C1P, C0P)) : 0.f;
        float ps = fmaxf(pSum[r] - psub, 0.f);
        ls += log1pf(ps) * (1.0f / F_ALPHA) + log1pf(nSum[r]) * (1.0f / F_BETA);
        nv += 1.f;
      }
    }
  }
#pragma unroll
  for (int d = 1; d < 64; d <<= 1) {
    ls += __shfl_xor(ls, d);
    nv += __shfl_xor(nv, d);
  }
  __shared__ float sL[16], sC[16];
  if ((t & 63) == 0) { sL[t >> 6] = ls; sC[t >> 6] = nv; }
  __syncthreads();
  if (t == 0) {
    float a = 0.f, c = 0.f;
#pragma unroll
    for (int w = 0; w < 16; ++w) { a += sL[w]; c += sC[w]; }
    out[0] = a / fmaxf(c, 1.f);
  }
}

extern "C" void kernel_launch(void* const* d_in, const int* in_sizes, int n_in,
                              void* d_out, int out_size, void* d_ws, size_t ws_size,
                              hipStream_t stream)
{
  const float* emb = (const float*)d_in[0];
  const int*   lab = (const int*)d_in[1];
  float* out = (float*)d_out;

  char* ws = (char*)d_ws;
  char*     P       = ws;                                       // 2 MB packed
  unsigned* pmKey   = (unsigned*)(ws + 2097152);                // 32 KB
  unsigned* nmKey   = (unsigned*)(ws + 2097152 + 32768);        // 32 KB
  float*    pSum    = (float*)(ws + 2097152 + 65536);           // 32 KB
  float*    nSum    = (float*)(ws + 2097152 + 98304);           // 32 KB
  float*    selfSim = (float*)(ws + 2097152 + 131072);          // 32 KB
  int*      cnt     = (int*)(ws + 2097152 + 163840);            // 2 KB

  hipMemsetAsync(cnt, 0, 512 * sizeof(int), stream);
  k_convert<<<NB * ND / (256 * 4), 256, 0, stream>>>(
      (const float4*)emb, P, lab, pmKey, nmKey, pSum, nSum, cnt);

  dim3 grid(16, 64);   // 16 col-chunks(512 cols) x 64 row-blocks
  k_simpass<0><<<grid, 256, 0, stream>>>(P, lab, pmKey, nmKey, pSum, nSum, selfSim);
  k_simpass<1><<<grid, 256, 0, stream>>>(P, lab, pmKey, nmKey, pSum, nSum, selfSim);
  k_final<<<1, 1024, 0, stream>>>(pmKey, nmKey, pSum, nSum, selfSim, lab, cnt, out);
}